// Round 1
// baseline (87.138 us; speedup 1.0000x reference)
//
#include <hip/hip_runtime.h>

#define NB 16      // batch
#define DD 128     // feature dim
#define NN 16      // nodes
#define NE 120     // edges (strict upper triangle of 16x16)

// edge index for a<p in triu_indices(16, k=1) row-major order
__device__ __forceinline__ int edge_idx(int a, int p) {
    return (a * (31 - a)) / 2 + (p - a - 1);
}

// ---------------------------------------------------------------------------
// Kernel T: T[b][lam][i][v] = sum_j relu(lam[i,j]+lam[j,i]) * F_tgt[b,j,v]
// grid = 256 blocks: b = blk>>4, lam = (blk>>3)&1, islice = blk&7
// block = 256 threads: i_local = t>>4, v = t&15
// ---------------------------------------------------------------------------
__global__ __launch_bounds__(256) void kT(const float* __restrict__ Ftgt,
                                          const float* __restrict__ lam1,
                                          const float* __restrict__ lam2,
                                          float* __restrict__ ws) {
    __shared__ float sFt[DD * NN];  // Ft[j][v] at j*16+v
    int blk = blockIdx.x;
    int b = blk >> 4;
    int lsel = (blk >> 3) & 1;
    int islice = blk & 7;
    int t = threadIdx.x;

    const float* F = Ftgt + b * (DD * NN);
    for (int k = t; k < DD * NN; k += 256) sFt[k] = F[k];
    __syncthreads();

    const float* lam = lsel ? lam2 : lam1;
    int i = (islice << 4) | (t >> 4);
    int v = t & 15;

    float acc = 0.f;
#pragma unroll 4
    for (int j = 0; j < DD; ++j) {
        float w = lam[i * DD + j] + lam[j * DD + i];
        w = fmaxf(w, 0.f);
        acc = fmaf(w, sFt[(j << 4) | v], acc);
    }
    // ws layout: T[b][lam][i][v] at ((b*2+lam)*128 + i)*16 + v
    ws[(((b * 2 + lsel) * DD) + i) * NN + v] = acc;
}

// ---------------------------------------------------------------------------
// Kernel P: per batch tables
//   P1[u][v] = sum_i F_src[b,i,u] * T1[i][v]
//   P2[u][v] = sum_i F_src[b,i,u] * T2[i][v]
//   Mp[u][v] = sum_d U_src[b,d,u] * U_tgt[b,d,v]
// grid = 16 (batch), block = 256: u = t>>4, v = t&15
// stored at ws + 65536 + b*768  (P1 | P2 | Mp, 256 each)
// ---------------------------------------------------------------------------
__global__ __launch_bounds__(256) void kP(const float* __restrict__ Fsrc,
                                          const float* __restrict__ Usrc,
                                          const float* __restrict__ Utgt,
                                          float* __restrict__ ws) {
    __shared__ float sFs[DD * NN];
    __shared__ float sT1[DD * NN];
    __shared__ float sT2[DD * NN];
    int b = blockIdx.x;
    int t = threadIdx.x;

    const float* F = Fsrc + b * (DD * NN);
    const float* T1 = ws + ((b * 2 + 0) * DD) * NN;
    const float* T2 = ws + ((b * 2 + 1) * DD) * NN;
    for (int k = t; k < DD * NN; k += 256) {
        sFs[k] = F[k];
        sT1[k] = T1[k];
        sT2[k] = T2[k];
    }
    __syncthreads();

    int u = t >> 4;
    int v = t & 15;

    float p1 = 0.f, p2 = 0.f;
#pragma unroll 4
    for (int i = 0; i < DD; ++i) {
        float fs = sFs[(i << 4) | u];
        p1 = fmaf(fs, sT1[(i << 4) | v], p1);
        p2 = fmaf(fs, sT2[(i << 4) | v], p2);
    }

    const float* Us = Usrc + b * (NN * NN);
    const float* Ut = Utgt + b * (NN * NN);
    float mp = 0.f;
#pragma unroll
    for (int d = 0; d < NN; ++d)
        mp = fmaf(Us[(d << 4) | u], Ut[(d << 4) | v], mp);

    float* out = ws + 65536 + b * 768;
    out[t] = p1;
    out[t + 256] = p2;
    out[t + 512] = mp;
}

// ---------------------------------------------------------------------------
// Kernel C: fill M[b, i, j], b in 16, i,j in 256.
//   i = (a,c) = (i>>4, i&15) [tgt node, src node of row], j = (p,q)
//   off-diag: if a<p, c<q, mboth[edge(a,p)], mboth[edge(c,q)]:
//       val = P1[a,c] + P2[p,c] + P2[a,q] + P1[p,q]
//   diag (i==j): += Mp[i]
// grid = 1024: b = blk>>6, rows r0 = (blk&63)*4; block = 256:
//   row = r0 + (t>>6), float4 col j0 = (t&63)*4
// ---------------------------------------------------------------------------
__global__ __launch_bounds__(256) void kC(const int* __restrict__ Asrc,
                                          const int* __restrict__ Atgt,
                                          const float* __restrict__ ws,
                                          float* __restrict__ out) {
    __shared__ float sP1[256];
    __shared__ float sP2[256];
    __shared__ float sMp[256];
    __shared__ int smask[128];

    int blk = blockIdx.x;
    int b = blk >> 6;
    int t = threadIdx.x;

    const float* tab = ws + 65536 + b * 768;
    sP1[t] = tab[t];
    sP2[t] = tab[t + 256];
    sMp[t] = tab[t + 512];
    if (t < NE) smask[t] = (Asrc[b * NE + t] > 0) && (Atgt[b * NE + t] > 0);
    __syncthreads();

    int r = ((blk & 63) << 2) | (t >> 6);   // row i in [0,256)
    int j0 = (t & 63) << 2;                 // col base
    int a = r >> 4, c = r & 15, p = j0 >> 4;

    bool condT = (a < p) && (smask[edge_idx(a, p)] != 0);
    float cpart = sP1[(a << 4) | c] + sP2[(p << 4) | c];

    float4 vec;
    float* vv = (float*)&vec;
#pragma unroll
    for (int s = 0; s < 4; ++s) {
        int j = j0 + s;
        int q = j & 15;
        float x = 0.f;
        if (condT && (c < q) && (smask[edge_idx(c, q)] != 0))
            x = cpart + sP2[(a << 4) | q] + sP1[(p << 4) | q];
        if (r == j) x += sMp[r];
        vv[s] = x;
    }
    *(float4*)(out + ((size_t)b << 16) + (r << 8) + j0) = vec;
}

extern "C" void kernel_launch(void* const* d_in, const int* in_sizes, int n_in,
                              void* d_out, int out_size, void* d_ws, size_t ws_size,
                              hipStream_t stream) {
    const int*   A_src  = (const int*)d_in[0];
    const int*   A_tgt  = (const int*)d_in[1];
    const float* F_src  = (const float*)d_in[2];
    const float* F_tgt  = (const float*)d_in[3];
    const float* U_src  = (const float*)d_in[4];
    const float* U_tgt  = (const float*)d_in[5];
    const float* lam1   = (const float*)d_in[6];
    const float* lam2   = (const float*)d_in[7];
    float* out = (float*)d_out;
    float* ws  = (float*)d_ws;   // needs (65536 + 16*768)*4 = 311 KB

    kT<<<256, 256, 0, stream>>>(F_tgt, lam1, lam2, ws);
    kP<<<16, 256, 0, stream>>>(F_src, U_src, U_tgt, ws);
    kC<<<1024, 256, 0, stream>>>(A_src, A_tgt, ws, out);
}